// Round 3
// baseline (1454.118 us; speedup 1.0000x reference)
//
#include <hip/hip_runtime.h>

// Problem constants: IN_C=512, HID=64, LOC=64, GLOB=64, OUT_C=40, K=10
// Propagation on C=40 channels (Wl_loc folded through W2).
// y layout SPLIT: ya = ch0..31 fp16, 64B rows (exactly one 64B sector/edge);
//                 yb = ch32..39 fp16, 16B rows packed (1.6MB -> L2-resident).
// This halves per-edge L3 gather traffic vs the old 80B-in-128B-stride rows.
// srcoff stores source NODE IDs; per-lane mul/add maps slot->address.
// mlp1 now uses fp16 MFMA (16x16x32) with fp32 accumulate.

typedef _Float16 half8 __attribute__((ext_vector_type(8)));
typedef _Float16 f16x8 __attribute__((ext_vector_type(8)));
typedef _Float16 f16x4 __attribute__((ext_vector_type(4)));
typedef float f32x4 __attribute__((ext_vector_type(4)));

// ---------------- CSR build ----------------

__global__ __launch_bounds__(256) void count_kernel(const int* __restrict__ edge,
                                                    int* __restrict__ counts, int E) {
  int e = blockIdx.x * 256 + threadIdx.x;
  if (e < E) atomicAdd(&counts[edge[E + e]], 1);  // target = edge_index[1]
}

// Phase A: bin (src,tgt) pairs into 49 coarse buckets (2048 nodes each).
__global__ __launch_bounds__(256) void bucketA_kernel(const int* __restrict__ edge,
                                                      unsigned long long* __restrict__ barr,
                                                      int* __restrict__ bcnt,
                                                      int E, int cap) {
  __shared__ int lcnt[64];
  __shared__ int lbase[64];
  int t = threadIdx.x;
  if (t < 64) lcnt[t] = 0;
  __syncthreads();
  int e0 = blockIdx.x * 2048 + t;
  int rk[8];
  int bk[8];
  unsigned long long pk[8];
#pragma unroll
  for (int i = 0; i < 8; ++i) {
    int e = e0 + i * 256;
    int s = 0, c = 0;
    if (e < E) { s = edge[e]; c = edge[E + e]; }
    int b = c >> 11;
    bk[i] = b;
    pk[i] = ((unsigned long long)(unsigned)c << 32) | (unsigned)s;
    if (e < E) rk[i] = atomicAdd(&lcnt[b], 1);
    else rk[i] = -1;
  }
  __syncthreads();
  if (t < 64 && lcnt[t] > 0) lbase[t] = atomicAdd(&bcnt[t], lcnt[t]);
  __syncthreads();
#pragma unroll
  for (int i = 0; i < 8; ++i)
    if (rk[i] >= 0)
      barr[(size_t)bk[i] * cap + lbase[bk[i]] + rk[i]] = pk[i];
}

// Phase B: scatter srcoff (node ids) per bucket, XCD-affine.
__global__ __launch_bounds__(256) void fillB_kernel(const unsigned long long* __restrict__ barr,
                                                    const int* __restrict__ bcnt,
                                                    const int* __restrict__ rowptr,
                                                    int* __restrict__ cursor,
                                                    int* __restrict__ srcoff,
                                                    int cap, int nb, int nbx, int cpb) {
  int i = blockIdx.x;
  int x = i & 7;
  int j = i >> 3;
  int bslot = j % nbx;
  int chunk = j / nbx;
  int b = x + 8 * bslot;
  if (b >= nb) return;
  int cnt = bcnt[b];
  int lo = (int)((long long)cnt * chunk / cpb);
  int hi = (int)((long long)cnt * (chunk + 1) / cpb);
  const unsigned long long* ep = barr + (size_t)b * cap;
  for (int e = lo + threadIdx.x; e < hi; e += 256) {
    unsigned long long pk = ep[e];
    int s = (int)(unsigned)pk;
    int c = (int)(pk >> 32);
    int p = rowptr[c] + atomicAdd(&cursor[c], 1);
    srcoff[p] = s;  // source node id
  }
}

__global__ __launch_bounds__(256) void scanA_kernel(const int* __restrict__ counts,
                                                    int* __restrict__ incl,
                                                    int* __restrict__ partials, int Nn) {
  __shared__ int sbuf[256];
  int t = threadIdx.x;
  int base = blockIdx.x * 1024 + t * 4;
  int a0 = (base + 0 < Nn) ? counts[base + 0] : 0;
  int a1 = (base + 1 < Nn) ? counts[base + 1] : 0;
  int a2 = (base + 2 < Nn) ? counts[base + 2] : 0;
  int a3 = (base + 3 < Nn) ? counts[base + 3] : 0;
  int tot = a0 + a1 + a2 + a3;
  sbuf[t] = tot;
  __syncthreads();
  for (int off = 1; off < 256; off <<= 1) {
    int v = (t >= off) ? sbuf[t - off] : 0;
    __syncthreads();
    sbuf[t] += v;
    __syncthreads();
  }
  int excl = sbuf[t] - tot;
  if (base + 0 < Nn) incl[base + 0] = excl + a0;
  if (base + 1 < Nn) incl[base + 1] = excl + a0 + a1;
  if (base + 2 < Nn) incl[base + 2] = excl + a0 + a1 + a2;
  if (base + 3 < Nn) incl[base + 3] = excl + tot;
  if (t == 255) partials[blockIdx.x] = sbuf[255];
}

__global__ void scanB_kernel(const int* __restrict__ partials,
                             int* __restrict__ chunkoff, int B) {
  __shared__ int sbuf[256];
  int t = threadIdx.x;
  int v = (t < B) ? partials[t] : 0;
  sbuf[t] = v;
  __syncthreads();
  for (int off = 1; off < 256; off <<= 1) {
    int u = (t >= off) ? sbuf[t - off] : 0;
    __syncthreads();
    sbuf[t] += u;
    __syncthreads();
  }
  chunkoff[t] = sbuf[t] - v;  // exclusive
}

__global__ __launch_bounds__(256) void finalize_scan_kernel(const int* __restrict__ incl,
                                                            const int* __restrict__ chunkoff,
                                                            int* __restrict__ rowptr, int Nn) {
  int i = blockIdx.x * 256 + threadIdx.x;
  if (i < Nn) rowptr[i + 1] = incl[i] + chunkoff[i >> 10];
  if (i == 0) rowptr[0] = 0;
}

__global__ __launch_bounds__(256) void dinv_kernel(const int* __restrict__ counts,
                                                   float* __restrict__ dinv, int Nn) {
  int i = blockIdx.x * 256 + threadIdx.x;
  if (i < Nn) dinv[i] = rsqrtf((float)(counts[i] + 1));  // +1 self-loop
}

// ---------------- W1 transpose+fp16 prep: W1T[col][k] ----------------

__global__ __launch_bounds__(256) void w1t_kernel(const float* __restrict__ W1,
                                                  _Float16* __restrict__ W1T) {
  int idx = blockIdx.x * 256 + threadIdx.x;  // 32768 total
  int col = idx >> 9;
  int k = idx & 511;
  W1T[col * 512 + k] = (_Float16)W1[k * 64 + col];
}

// ---------------- MLP stage 1 via MFMA: H = relu(X @ W1 + b1) ----------------
// 64-row tile per block, 4 waves; wave w owns rows 16w..16w+15 x all 64 cols.
// A frag: row=lane&15, k=(lane>>4)*8+j ; B frag: col=lane&15, same k map;
// D: col=lane&15, row=(lane>>4)*4+reg (m89-verified layout).

__global__ __launch_bounds__(256) void mlp1_mfma_kernel(const float* __restrict__ X,
                                                        const _Float16* __restrict__ W1T,
                                                        const float* __restrict__ b1,
                                                        float* __restrict__ H, int Nn) {
  __shared__ _Float16 sX[64][88];   // [row][k] fp16, stride 176B (16B-aligned, 2-way banks)
  __shared__ _Float16 sWT[64][88];  // [col][k] fp16
  int t = threadIdx.x;
  int m0 = blockIdx.x * 64;
  int lane = t & 63, w = t >> 6;
  f32x4 acc[4];
#pragma unroll
  for (int i = 0; i < 4; ++i) acc[i] = (f32x4){0.f, 0.f, 0.f, 0.f};
  int l15 = lane & 15;
  int kgrp = (lane >> 4) * 8;

  for (int k0 = 0; k0 < 512; k0 += 64) {
    // stage X tile: 64 rows x 64 k, fp32->fp16
#pragma unroll
    for (int i = 0; i < 4; ++i) {
      int lin = t + i * 256;
      int m = lin >> 4;
      int kq = (lin & 15) * 4;
      float4 v = make_float4(0.f, 0.f, 0.f, 0.f);
      if (m0 + m < Nn) v = *(const float4*)&X[(size_t)(m0 + m) * 512 + k0 + kq];
      f16x4 h4 = {(_Float16)v.x, (_Float16)v.y, (_Float16)v.z, (_Float16)v.w};
      *(f16x4*)&sX[m][kq] = h4;
    }
    // stage W1T tile: 64 cols x 64 k (already fp16, contiguous in k)
#pragma unroll
    for (int i = 0; i < 2; ++i) {
      int c = t + i * 256;       // 512 chunks of 8 halves
      int col = c >> 3;
      int k8 = (c & 7) * 8;
      f16x8 v = *(const f16x8*)&W1T[col * 512 + k0 + k8];
      *(f16x8*)&sWT[col][k8] = v;
    }
    __syncthreads();
#pragma unroll
    for (int kc = 0; kc < 2; ++kc) {
      f16x8 a = *(const f16x8*)&sX[16 * w + l15][kc * 32 + kgrp];
#pragma unroll
      for (int c = 0; c < 4; ++c) {
        f16x8 b = *(const f16x8*)&sWT[c * 16 + l15][kc * 32 + kgrp];
        acc[c] = __builtin_amdgcn_mfma_f32_16x16x32_f16(a, b, acc[c], 0, 0, 0);
      }
    }
    __syncthreads();
  }
  int rbase = m0 + 16 * w + (lane >> 4) * 4;
#pragma unroll
  for (int c = 0; c < 4; ++c) {
    float bias = b1[c * 16 + l15];
#pragma unroll
    for (int r = 0; r < 4; ++r) {
      int row = rbase + r;
      if (row < Nn) H[(size_t)row * 64 + c * 16 + l15] = fmaxf(acc[c][r] + bias, 0.f);
    }
  }
}

// ---------------- M = W2 @ Wl[:64], cv = b2 @ Wl[:64] ----------------

__global__ void computeM_kernel(const float* __restrict__ W2, const float* __restrict__ Wl,
                                const float* __restrict__ b2, float* __restrict__ Mm,
                                float* __restrict__ cv) {
  int t = threadIdx.x;
  for (int idx = t; idx < 2560; idx += 256) {
    int k = idx / 40, o = idx - k * 40;
    float s = 0.f;
    for (int j = 0; j < 64; ++j) s += W2[k * 64 + j] * Wl[j * 40 + o];
    Mm[idx] = s;
  }
  if (t < 40) {
    float s = 0.f;
    for (int j = 0; j < 64; ++j) s += b2[j] * Wl[j * 40 + t];
    cv[t] = s;
  }
}

__global__ void zeropad_kernel(char* __restrict__ yA, char* __restrict__ yB,
                               int Nn, int yboff) {
  int t = threadIdx.x;  // 64 threads zero pad rows (ya: 32 halves, yb: 8 halves)
  if (t < 32) {
    ((_Float16*)(yA + (size_t)Nn * 64))[t] = (_Float16)0.f;
    ((_Float16*)(yB + (size_t)Nn * 64))[t] = (_Float16)0.f;
  } else if (t < 40) {
    ((_Float16*)(yA + yboff + (size_t)Nn * 16))[t - 32] = (_Float16)0.f;
    ((_Float16*)(yB + yboff + (size_t)Nn * 16))[t - 32] = (_Float16)0.f;
  }
}

// ---------------- z0: y0 = dinv * (H @ M + cv) (fp16 split); hid = temp[0]*y0 ----------------

__global__ __launch_bounds__(256) void z0_kernel(const float* __restrict__ H,
                                                 const float* __restrict__ Mm,
                                                 const float* __restrict__ cv,
                                                 const float* __restrict__ dinv,
                                                 const float* __restrict__ temp,
                                                 char* __restrict__ y0,
                                                 float* __restrict__ hid, int Nn, int yboff) {
  __shared__ float sM[2624];
  __shared__ float sc[40];
  int t = threadIdx.x;
  for (int i = t; i < 2560; i += 256) sM[i] = Mm[i];
  for (int i = 2560 + t; i < 2624; i += 256) sM[i] = 0.f;
  if (t < 40) sc[t] = cv[t];
  __syncthreads();
  int wid = t >> 6, lane = t & 63;
  int node = blockIdx.x * 4 + wid;
  if (node < Nn) {
    float h = H[(size_t)node * 64 + lane];
    float acc = (lane < 40) ? sc[lane] : 0.f;
#pragma unroll 8
    for (int k = 0; k < 64; ++k) acc += __shfl(h, k) * sM[k * 40 + lane];
    if (lane < 40) {
      float di = dinv[node];
      float y = di * acc;
      if (lane < 32)
        ((_Float16*)(y0 + (size_t)node * 64))[lane] = (_Float16)y;
      else
        ((_Float16*)(y0 + yboff + (size_t)node * 16))[lane - 32] = (_Float16)y;
      hid[(size_t)node * 40 + lane] = temp[0] * y;
    }
  }
}

// ---------------- propagation hop (split fp16 y) ----------------
// slot cl<4 reads ya (64B rows), cl==4 reads yb (16B rows, L2-resident).

__global__ __launch_bounds__(256) void prop_kernel(const char* __restrict__ yin,
                                                   char* __restrict__ yout,
                                                   float* __restrict__ hid,
                                                   const int* __restrict__ srcoff,
                                                   const int* __restrict__ rowptr,
                                                   const float* __restrict__ dinv,
                                                   const float* __restrict__ temp,
                                                   int kidx, int Nn, int yboff) {
  __shared__ float red[4][60][8];
  int t = threadIdx.x, wid = t >> 6, lane = t & 63;
  int node = blockIdx.x * 4 + wid;
  int sub = lane / 5;        // edge group 0..11 (12 for lanes 60..63 -> pad)
  int cl = lane - sub * 5;   // slot 0..4
  int lmul = (cl == 4) ? 16 : 64;
  int ladd = (cl == 4) ? yboff : (cl << 4);
  float a0 = 0.f, a1 = 0.f, a2 = 0.f, a3 = 0.f, a4 = 0.f, a5 = 0.f, a6 = 0.f, a7 = 0.f;
  if (node < Nn) {
    int start = rowptr[node], end = rowptr[node + 1];
    for (int b0 = start; b0 < end; b0 += 60) {
      int j = b0 + lane;
      int msrc = (lane < 60 && j < end) ? srcoff[j] : Nn;  // pad node id
#pragma unroll
      for (int tt = 0; tt < 5; ++tt) {
        int n = __shfl(msrc, tt * 12 + sub);
        half8 v = *(const half8*)(yin + (size_t)(n * lmul + ladd));
        a0 += (float)v[0]; a1 += (float)v[1]; a2 += (float)v[2]; a3 += (float)v[3];
        a4 += (float)v[4]; a5 += (float)v[5]; a6 += (float)v[6]; a7 += (float)v[7];
      }
    }
  }
  if (lane < 60) {
    red[wid][lane][0] = a0; red[wid][lane][1] = a1;
    red[wid][lane][2] = a2; red[wid][lane][3] = a3;
    red[wid][lane][4] = a4; red[wid][lane][5] = a5;
    red[wid][lane][6] = a6; red[wid][lane][7] = a7;
  }
  __syncthreads();
  if (node < Nn && lane < 5) {
    float s[8];
#pragma unroll
    for (int i = 0; i < 8; ++i) s[i] = 0.f;
#pragma unroll
    for (int g = 0; g < 12; ++g)
#pragma unroll
      for (int i = 0; i < 8; ++i) s[i] += red[wid][g * 5 + lane][i];
    float di = dinv[node];
    float m = di * di;
    int lm2 = (lane == 4) ? 16 : 64;
    int la2 = (lane == 4) ? yboff : (lane << 4);
    half8 self = *(const half8*)(yin + (size_t)(node * lm2 + la2));
    float yn[8];
    half8 outv;
#pragma unroll
    for (int i = 0; i < 8; ++i) {
      yn[i] = m * (s[i] + (float)self[i]);
      outv[i] = (_Float16)yn[i];
    }
    *(half8*)(yout + (size_t)(node * lm2 + la2)) = outv;
    float tk = temp[kidx];
    float* hp = &hid[(size_t)node * 40 + lane * 8];
    float4 h0 = *(float4*)hp;
    float4 h1 = *(float4*)(hp + 4);
    h0.x += tk * yn[0]; h0.y += tk * yn[1]; h0.z += tk * yn[2]; h0.w += tk * yn[3];
    h1.x += tk * yn[4]; h1.y += tk * yn[5]; h1.z += tk * yn[6]; h1.w += tk * yn[7];
    *(float4*)hp = h0;
    *(float4*)(hp + 4) = h1;
  }
}

// ---------------- final: out = sqrt(deg)*hid + glob @ Wl[64:] + bl ----------------

__global__ __launch_bounds__(256) void final_kernel(const float* __restrict__ glob,
                                                    const float* __restrict__ Wl,
                                                    const float* __restrict__ bl,
                                                    const float* __restrict__ hid,
                                                    const int* __restrict__ counts,
                                                    const float* __restrict__ dinv,
                                                    float* __restrict__ out, int Nn) {
  __shared__ float sW[2624];
  __shared__ float sb[40];
  int t = threadIdx.x;
  for (int i = t; i < 2560; i += 256) sW[i] = Wl[2560 + i];  // Wl[64:128,:]
  for (int i = 2560 + t; i < 2624; i += 256) sW[i] = 0.f;
  if (t < 40) sb[t] = bl[t];
  __syncthreads();
  int wid = t >> 6, lane = t & 63;
  int node = blockIdx.x * 4 + wid;
  if (node < Nn) {
    float g = glob[(size_t)node * 64 + lane];
    float acc = (lane < 40) ? sb[lane] : 0.f;
#pragma unroll 8
    for (int k = 0; k < 64; ++k) acc += __shfl(g, k) * sW[k * 40 + lane];
    if (lane < 40) {
      float sc = (float)(counts[node] + 1) * dinv[node];  // sqrt(deg)
      out[(size_t)node * 40 + lane] = sc * hid[(size_t)node * 40 + lane] + acc;
    }
  }
}

// ---------------- host ----------------

extern "C" void kernel_launch(void* const* d_in, const int* in_sizes, int n_in,
                              void* d_out, int out_size, void* d_ws, size_t ws_size,
                              hipStream_t stream) {
  const float* X    = (const float*)d_in[0];
  const int*   edge = (const int*)d_in[1];
  const float* glob = (const float*)d_in[2];
  const float* W1   = (const float*)d_in[3];
  const float* b1   = (const float*)d_in[4];
  const float* W2   = (const float*)d_in[5];
  const float* b2   = (const float*)d_in[6];
  const float* temp = (const float*)d_in[7];
  const float* Wl   = (const float*)d_in[8];
  const float* bl   = (const float*)d_in[9];
  float* out = (float*)d_out;

  int Nn = in_sizes[0] / 512;     // 100000
  int E  = in_sizes[1] / 2;       // 3200000
  int Kk = in_sizes[7] - 1;       // 10

  char* p = (char*)d_ws;
  auto alloc = [&](size_t bytes) {
    char* r = p;
    p += (bytes + 255) & ~(size_t)255;
    return r;
  };
  int*   counts   = (int*)alloc((size_t)Nn * 4);
  int*   rowptr   = (int*)alloc((size_t)(Nn + 1) * 4);
  int*   incl     = (int*)alloc((size_t)Nn * 4);
  int*   partials = (int*)alloc(256 * 4);
  int*   chunkoff = (int*)alloc(256 * 4);
  int*   cursor   = (int*)alloc((size_t)Nn * 4);
  float* dinv     = (float*)alloc((size_t)Nn * 4);
  int*   srcoff   = (int*)alloc((size_t)E * 4);
  float* Hbuf     = (float*)alloc((size_t)Nn * 64 * 4);
  float* Mm       = (float*)alloc(2560 * 4);
  float* cv       = (float*)alloc(64 * 4);
  _Float16* W1T   = (_Float16*)alloc(64 * 512 * 2);
  int yboff = (Nn + 1) * 64;                       // byte offset of yb region
  size_t ybytes = (size_t)(Nn + 1) * 80;           // ya (64B rows) + yb (16B rows)
  char*  yA       = (char*)alloc(ybytes);
  char*  yB       = (char*)alloc(ybytes);
  float* hid      = (float*)alloc((size_t)Nn * 40 * 4);

  // bucketed CSR-build scratch
  int nb  = (Nn + 2047) >> 11;          // 49 buckets of 2048 nodes
  int nbx = (nb + 7) / 8;               // bucket slots per XCD class
  int cap = E / nb + E / (nb * 8) + 1024;  // per-bucket capacity (~13% headroom)
  unsigned long long* barr = (unsigned long long*)alloc((size_t)nb * cap * 8);
  int* bcnt = (int*)alloc(64 * 4);

  hipMemsetAsync(counts, 0, (size_t)Nn * 4, stream);
  hipMemsetAsync(cursor, 0, (size_t)Nn * 4, stream);
  hipMemsetAsync(bcnt, 0, 64 * 4, stream);

  count_kernel<<<(E + 255) / 256, 256, 0, stream>>>(edge, counts, E);
  bucketA_kernel<<<(E + 2047) / 2048, 256, 0, stream>>>(edge, barr, bcnt, E, cap);
  int B = (Nn + 1023) / 1024;
  scanA_kernel<<<B, 256, 0, stream>>>(counts, incl, partials, Nn);
  scanB_kernel<<<1, 256, 0, stream>>>(partials, chunkoff, B);
  finalize_scan_kernel<<<(Nn + 255) / 256, 256, 0, stream>>>(incl, chunkoff, rowptr, Nn);
  dinv_kernel<<<(Nn + 255) / 256, 256, 0, stream>>>(counts, dinv, Nn);
  int cpb = 32;
  fillB_kernel<<<8 * nbx * cpb, 256, 0, stream>>>(barr, bcnt, rowptr, cursor, srcoff,
                                                  cap, nb, nbx, cpb);

  w1t_kernel<<<128, 256, 0, stream>>>(W1, W1T);
  mlp1_mfma_kernel<<<(Nn + 63) / 64, 256, 0, stream>>>(X, W1T, b1, Hbuf, Nn);
  computeM_kernel<<<1, 256, 0, stream>>>(W2, Wl, b2, Mm, cv);
  zeropad_kernel<<<1, 64, 0, stream>>>(yA, yB, Nn, yboff);

  int nodeBlocks = (Nn + 3) / 4;
  z0_kernel<<<nodeBlocks, 256, 0, stream>>>(Hbuf, Mm, cv, dinv, temp, yA, hid, Nn, yboff);

  char* yin = yA;
  char* yout = yB;
  for (int k = 1; k <= Kk; ++k) {
    prop_kernel<<<nodeBlocks, 256, 0, stream>>>(yin, yout, hid, srcoff, rowptr, dinv,
                                                temp, k, Nn, yboff);
    char* tmpp = yin; yin = yout; yout = tmpp;
  }

  final_kernel<<<nodeBlocks, 256, 0, stream>>>(glob, Wl, bl, hid, counts, dinv, out, Nn);
}

// Round 4
// 1392.347 us; speedup vs baseline: 1.0444x; 1.0444x over previous
//
#include <hip/hip_runtime.h>

// Problem constants: IN_C=512, HID=64, LOC=64, GLOB=64, OUT_C=40, K=10
// Propagation on C=40 channels (Wl_loc folded through W2).
// y layout SPLIT: ya = ch0..31 fp16, 64B rows (one 64B sector/edge);
//                 yb = ch32..39 fp16, 16B rows packed (1.6MB -> L2-resident).
// CSR build: bucketA bins (tgt,src) by tgt>>11; countB LDS-histograms each
// bucket (replaces 3.2M global atomics that cost 128us in HBM writebacks);
// fillB scatters srcoff XCD-affine. mlp1 uses fp16 MFMA.

typedef _Float16 half8 __attribute__((ext_vector_type(8)));
typedef _Float16 f16x8 __attribute__((ext_vector_type(8)));
typedef _Float16 f16x4 __attribute__((ext_vector_type(4)));
typedef float f32x4 __attribute__((ext_vector_type(4)));

// ---------------- CSR build ----------------

// Phase A: bin (src,tgt) pairs into 49 coarse buckets (2048 nodes each).
__global__ __launch_bounds__(256) void bucketA_kernel(const int* __restrict__ edge,
                                                      unsigned long long* __restrict__ barr,
                                                      int* __restrict__ bcnt,
                                                      int E, int cap) {
  __shared__ int lcnt[64];
  __shared__ int lbase[64];
  int t = threadIdx.x;
  if (t < 64) lcnt[t] = 0;
  __syncthreads();
  int e0 = blockIdx.x * 2048 + t;
  int rk[8];
  int bk[8];
  unsigned long long pk[8];
#pragma unroll
  for (int i = 0; i < 8; ++i) {
    int e = e0 + i * 256;
    int s = 0, c = 0;
    if (e < E) { s = edge[e]; c = edge[E + e]; }
    int b = c >> 11;
    bk[i] = b;
    pk[i] = ((unsigned long long)(unsigned)c << 32) | (unsigned)s;
    if (e < E) rk[i] = atomicAdd(&lcnt[b], 1);
    else rk[i] = -1;
  }
  __syncthreads();
  if (t < 64 && lcnt[t] > 0) lbase[t] = atomicAdd(&bcnt[t], lcnt[t]);
  __syncthreads();
#pragma unroll
  for (int i = 0; i < 8; ++i)
    if (rk[i] >= 0)
      barr[(size_t)bk[i] * cap + lbase[bk[i]] + rk[i]] = pk[i];
}

// countB: per-bucket LDS histogram -> counts + dinv, contiguous writes,
// no global atomics. Replaces count_kernel (was 128us) + dinv_kernel.
__global__ __launch_bounds__(256) void countB_kernel(const unsigned long long* __restrict__ barr,
                                                     const int* __restrict__ bcnt,
                                                     int* __restrict__ counts,
                                                     float* __restrict__ dinv,
                                                     int cap, int Nn) {
  __shared__ int h[2048];
  int b = blockIdx.x;
  int t = threadIdx.x;
  for (int i = t; i < 2048; i += 256) h[i] = 0;
  __syncthreads();
  int cnt = bcnt[b];
  const unsigned long long* ep = barr + (size_t)b * cap;
  int base = b << 11;
  for (int e = t; e < cnt; e += 256) {
    int c = (int)(ep[e] >> 32);
    atomicAdd(&h[c - base], 1);
  }
  __syncthreads();
  for (int i = t; i < 2048; i += 256) {
    int node = base + i;
    if (node < Nn) {
      int d = h[i];
      counts[node] = d;
      dinv[node] = rsqrtf((float)(d + 1));  // +1 self-loop
    }
  }
}

// Phase B: scatter srcoff (node ids) per bucket, XCD-affine.
__global__ __launch_bounds__(256) void fillB_kernel(const unsigned long long* __restrict__ barr,
                                                    const int* __restrict__ bcnt,
                                                    const int* __restrict__ rowptr,
                                                    int* __restrict__ cursor,
                                                    int* __restrict__ srcoff,
                                                    int cap, int nb, int nbx, int cpb) {
  int i = blockIdx.x;
  int x = i & 7;
  int j = i >> 3;
  int bslot = j % nbx;
  int chunk = j / nbx;
  int b = x + 8 * bslot;
  if (b >= nb) return;
  int cnt = bcnt[b];
  int lo = (int)((long long)cnt * chunk / cpb);
  int hi = (int)((long long)cnt * (chunk + 1) / cpb);
  const unsigned long long* ep = barr + (size_t)b * cap;
  for (int e = lo + threadIdx.x; e < hi; e += 256) {
    unsigned long long pk = ep[e];
    int s = (int)(unsigned)pk;
    int c = (int)(pk >> 32);
    int p = rowptr[c] + atomicAdd(&cursor[c], 1);
    srcoff[p] = s;  // source node id
  }
}

__global__ __launch_bounds__(256) void scanA_kernel(const int* __restrict__ counts,
                                                    int* __restrict__ incl,
                                                    int* __restrict__ partials, int Nn) {
  __shared__ int sbuf[256];
  int t = threadIdx.x;
  int base = blockIdx.x * 1024 + t * 4;
  int a0 = (base + 0 < Nn) ? counts[base + 0] : 0;
  int a1 = (base + 1 < Nn) ? counts[base + 1] : 0;
  int a2 = (base + 2 < Nn) ? counts[base + 2] : 0;
  int a3 = (base + 3 < Nn) ? counts[base + 3] : 0;
  int tot = a0 + a1 + a2 + a3;
  sbuf[t] = tot;
  __syncthreads();
  for (int off = 1; off < 256; off <<= 1) {
    int v = (t >= off) ? sbuf[t - off] : 0;
    __syncthreads();
    sbuf[t] += v;
    __syncthreads();
  }
  int excl = sbuf[t] - tot;
  if (base + 0 < Nn) incl[base + 0] = excl + a0;
  if (base + 1 < Nn) incl[base + 1] = excl + a0 + a1;
  if (base + 2 < Nn) incl[base + 2] = excl + a0 + a1 + a2;
  if (base + 3 < Nn) incl[base + 3] = excl + tot;
  if (t == 255) partials[blockIdx.x] = sbuf[255];
}

__global__ void scanB_kernel(const int* __restrict__ partials,
                             int* __restrict__ chunkoff, int B) {
  __shared__ int sbuf[256];
  int t = threadIdx.x;
  int v = (t < B) ? partials[t] : 0;
  sbuf[t] = v;
  __syncthreads();
  for (int off = 1; off < 256; off <<= 1) {
    int u = (t >= off) ? sbuf[t - off] : 0;
    __syncthreads();
    sbuf[t] += u;
    __syncthreads();
  }
  chunkoff[t] = sbuf[t] - v;  // exclusive
}

__global__ __launch_bounds__(256) void finalize_scan_kernel(const int* __restrict__ incl,
                                                            const int* __restrict__ chunkoff,
                                                            int* __restrict__ rowptr, int Nn) {
  int i = blockIdx.x * 256 + threadIdx.x;
  if (i < Nn) rowptr[i + 1] = incl[i] + chunkoff[i >> 10];
  if (i == 0) rowptr[0] = 0;
}

// ---------------- W1 transpose+fp16 prep: W1T[col][k] ----------------

__global__ __launch_bounds__(256) void w1t_kernel(const float* __restrict__ W1,
                                                  _Float16* __restrict__ W1T) {
  int idx = blockIdx.x * 256 + threadIdx.x;  // 32768 total
  int col = idx >> 9;
  int k = idx & 511;
  W1T[col * 512 + k] = (_Float16)W1[k * 64 + col];
}

// ---------------- MLP stage 1 via MFMA: H = relu(X @ W1 + b1) ----------------

__global__ __launch_bounds__(256) void mlp1_mfma_kernel(const float* __restrict__ X,
                                                        const _Float16* __restrict__ W1T,
                                                        const float* __restrict__ b1,
                                                        float* __restrict__ H, int Nn) {
  __shared__ _Float16 sX[64][88];   // [row][k] fp16
  __shared__ _Float16 sWT[64][88];  // [col][k] fp16
  int t = threadIdx.x;
  int m0 = blockIdx.x * 64;
  int lane = t & 63, w = t >> 6;
  f32x4 acc[4];
#pragma unroll
  for (int i = 0; i < 4; ++i) acc[i] = (f32x4){0.f, 0.f, 0.f, 0.f};
  int l15 = lane & 15;
  int kgrp = (lane >> 4) * 8;

  for (int k0 = 0; k0 < 512; k0 += 64) {
#pragma unroll
    for (int i = 0; i < 4; ++i) {
      int lin = t + i * 256;
      int m = lin >> 4;
      int kq = (lin & 15) * 4;
      float4 v = make_float4(0.f, 0.f, 0.f, 0.f);
      if (m0 + m < Nn) v = *(const float4*)&X[(size_t)(m0 + m) * 512 + k0 + kq];
      f16x4 h4 = {(_Float16)v.x, (_Float16)v.y, (_Float16)v.z, (_Float16)v.w};
      *(f16x4*)&sX[m][kq] = h4;
    }
#pragma unroll
    for (int i = 0; i < 2; ++i) {
      int c = t + i * 256;       // 512 chunks of 8 halves
      int col = c >> 3;
      int k8 = (c & 7) * 8;
      f16x8 v = *(const f16x8*)&W1T[col * 512 + k0 + k8];
      *(f16x8*)&sWT[col][k8] = v;
    }
    __syncthreads();
#pragma unroll
    for (int kc = 0; kc < 2; ++kc) {
      f16x8 a = *(const f16x8*)&sX[16 * w + l15][kc * 32 + kgrp];
#pragma unroll
      for (int c = 0; c < 4; ++c) {
        f16x8 b = *(const f16x8*)&sWT[c * 16 + l15][kc * 32 + kgrp];
        acc[c] = __builtin_amdgcn_mfma_f32_16x16x32_f16(a, b, acc[c], 0, 0, 0);
      }
    }
    __syncthreads();
  }
  int rbase = m0 + 16 * w + (lane >> 4) * 4;
#pragma unroll
  for (int c = 0; c < 4; ++c) {
    float bias = b1[c * 16 + l15];
#pragma unroll
    for (int r = 0; r < 4; ++r) {
      int row = rbase + r;
      if (row < Nn) H[(size_t)row * 64 + c * 16 + l15] = fmaxf(acc[c][r] + bias, 0.f);
    }
  }
}

// ---------------- M = W2 @ Wl[:64], cv = b2 @ Wl[:64] ----------------

__global__ void computeM_kernel(const float* __restrict__ W2, const float* __restrict__ Wl,
                                const float* __restrict__ b2, float* __restrict__ Mm,
                                float* __restrict__ cv) {
  int t = threadIdx.x;
  for (int idx = t; idx < 2560; idx += 256) {
    int k = idx / 40, o = idx - k * 40;
    float s = 0.f;
    for (int j = 0; j < 64; ++j) s += W2[k * 64 + j] * Wl[j * 40 + o];
    Mm[idx] = s;
  }
  if (t < 40) {
    float s = 0.f;
    for (int j = 0; j < 64; ++j) s += b2[j] * Wl[j * 40 + t];
    cv[t] = s;
  }
}

__global__ void zeropad_kernel(char* __restrict__ yA, char* __restrict__ yB,
                               int Nn, int yboff) {
  int t = threadIdx.x;  // pad rows (ya: 32 halves, yb: 8 halves)
  if (t < 32) {
    ((_Float16*)(yA + (size_t)Nn * 64))[t] = (_Float16)0.f;
    ((_Float16*)(yB + (size_t)Nn * 64))[t] = (_Float16)0.f;
  } else if (t < 40) {
    ((_Float16*)(yA + yboff + (size_t)Nn * 16))[t - 32] = (_Float16)0.f;
    ((_Float16*)(yB + yboff + (size_t)Nn * 16))[t - 32] = (_Float16)0.f;
  }
}

// ---------------- z0: y0 = dinv * (H @ M + cv) (fp16 split); hid = temp[0]*y0 ----------------

__global__ __launch_bounds__(256) void z0_kernel(const float* __restrict__ H,
                                                 const float* __restrict__ Mm,
                                                 const float* __restrict__ cv,
                                                 const float* __restrict__ dinv,
                                                 const float* __restrict__ temp,
                                                 char* __restrict__ y0,
                                                 float* __restrict__ hid, int Nn, int yboff) {
  __shared__ float sM[2624];
  __shared__ float sc[40];
  int t = threadIdx.x;
  for (int i = t; i < 2560; i += 256) sM[i] = Mm[i];
  for (int i = 2560 + t; i < 2624; i += 256) sM[i] = 0.f;
  if (t < 40) sc[t] = cv[t];
  __syncthreads();
  int wid = t >> 6, lane = t & 63;
  int node = blockIdx.x * 4 + wid;
  if (node < Nn) {
    float h = H[(size_t)node * 64 + lane];
    float acc = (lane < 40) ? sc[lane] : 0.f;
#pragma unroll 8
    for (int k = 0; k < 64; ++k) acc += __shfl(h, k) * sM[k * 40 + lane];
    if (lane < 40) {
      float di = dinv[node];
      float y = di * acc;
      if (lane < 32)
        ((_Float16*)(y0 + (size_t)node * 64))[lane] = (_Float16)y;
      else
        ((_Float16*)(y0 + yboff + (size_t)node * 16))[lane - 32] = (_Float16)y;
      hid[(size_t)node * 40 + lane] = temp[0] * y;
    }
  }
}

// ---------------- propagation hop (split fp16 y) ----------------

__global__ __launch_bounds__(256) void prop_kernel(const char* __restrict__ yin,
                                                   char* __restrict__ yout,
                                                   float* __restrict__ hid,
                                                   const int* __restrict__ srcoff,
                                                   const int* __restrict__ rowptr,
                                                   const float* __restrict__ dinv,
                                                   const float* __restrict__ temp,
                                                   int kidx, int Nn, int yboff) {
  __shared__ float red[4][60][8];
  int t = threadIdx.x, wid = t >> 6, lane = t & 63;
  int node = blockIdx.x * 4 + wid;
  int sub = lane / 5;        // edge group 0..11 (12 for lanes 60..63 -> pad)
  int cl = lane - sub * 5;   // slot 0..4
  int lmul = (cl == 4) ? 16 : 64;
  int ladd = (cl == 4) ? yboff : (cl << 4);
  float a0 = 0.f, a1 = 0.f, a2 = 0.f, a3 = 0.f, a4 = 0.f, a5 = 0.f, a6 = 0.f, a7 = 0.f;
  if (node < Nn) {
    int start = rowptr[node], end = rowptr[node + 1];
    for (int b0 = start; b0 < end; b0 += 60) {
      int j = b0 + lane;
      int msrc = (lane < 60 && j < end) ? srcoff[j] : Nn;  // pad node id
#pragma unroll
      for (int tt = 0; tt < 5; ++tt) {
        int n = __shfl(msrc, tt * 12 + sub);
        half8 v = *(const half8*)(yin + (size_t)(n * lmul + ladd));
        a0 += (float)v[0]; a1 += (float)v[1]; a2 += (float)v[2]; a3 += (float)v[3];
        a4 += (float)v[4]; a5 += (float)v[5]; a6 += (float)v[6]; a7 += (float)v[7];
      }
    }
  }
  if (lane < 60) {
    red[wid][lane][0] = a0; red[wid][lane][1] = a1;
    red[wid][lane][2] = a2; red[wid][lane][3] = a3;
    red[wid][lane][4] = a4; red[wid][lane][5] = a5;
    red[wid][lane][6] = a6; red[wid][lane][7] = a7;
  }
  __syncthreads();
  if (node < Nn && lane < 5) {
    float s[8];
#pragma unroll
    for (int i = 0; i < 8; ++i) s[i] = 0.f;
#pragma unroll
    for (int g = 0; g < 12; ++g)
#pragma unroll
      for (int i = 0; i < 8; ++i) s[i] += red[wid][g * 5 + lane][i];
    float di = dinv[node];
    float m = di * di;
    int lm2 = (lane == 4) ? 16 : 64;
    int la2 = (lane == 4) ? yboff : (lane << 4);
    half8 self = *(const half8*)(yin + (size_t)(node * lm2 + la2));
    float yn[8];
    half8 outv;
#pragma unroll
    for (int i = 0; i < 8; ++i) {
      yn[i] = m * (s[i] + (float)self[i]);
      outv[i] = (_Float16)yn[i];
    }
    *(half8*)(yout + (size_t)(node * lm2 + la2)) = outv;
    float tk = temp[kidx];
    float* hp = &hid[(size_t)node * 40 + lane * 8];
    float4 h0 = *(float4*)hp;
    float4 h1 = *(float4*)(hp + 4);
    h0.x += tk * yn[0]; h0.y += tk * yn[1]; h0.z += tk * yn[2]; h0.w += tk * yn[3];
    h1.x += tk * yn[4]; h1.y += tk * yn[5]; h1.z += tk * yn[6]; h1.w += tk * yn[7];
    *(float4*)hp = h0;
    *(float4*)(hp + 4) = h1;
  }
}

// ---------------- final: out = sqrt(deg)*hid + glob @ Wl[64:] + bl ----------------

__global__ __launch_bounds__(256) void final_kernel(const float* __restrict__ glob,
                                                    const float* __restrict__ Wl,
                                                    const float* __restrict__ bl,
                                                    const float* __restrict__ hid,
                                                    const int* __restrict__ counts,
                                                    const float* __restrict__ dinv,
                                                    float* __restrict__ out, int Nn) {
  __shared__ float sW[2624];
  __shared__ float sb[40];
  int t = threadIdx.x;
  for (int i = t; i < 2560; i += 256) sW[i] = Wl[2560 + i];  // Wl[64:128,:]
  for (int i = 2560 + t; i < 2624; i += 256) sW[i] = 0.f;
  if (t < 40) sb[t] = bl[t];
  __syncthreads();
  int wid = t >> 6, lane = t & 63;
  int node = blockIdx.x * 4 + wid;
  if (node < Nn) {
    float g = glob[(size_t)node * 64 + lane];
    float acc = (lane < 40) ? sb[lane] : 0.f;
#pragma unroll 8
    for (int k = 0; k < 64; ++k) acc += __shfl(g, k) * sW[k * 40 + lane];
    if (lane < 40) {
      float sc = (float)(counts[node] + 1) * dinv[node];  // sqrt(deg)
      out[(size_t)node * 40 + lane] = sc * hid[(size_t)node * 40 + lane] + acc;
    }
  }
}

// ---------------- host ----------------

extern "C" void kernel_launch(void* const* d_in, const int* in_sizes, int n_in,
                              void* d_out, int out_size, void* d_ws, size_t ws_size,
                              hipStream_t stream) {
  const float* X    = (const float*)d_in[0];
  const int*   edge = (const int*)d_in[1];
  const float* glob = (const float*)d_in[2];
  const float* W1   = (const float*)d_in[3];
  const float* b1   = (const float*)d_in[4];
  const float* W2   = (const float*)d_in[5];
  const float* b2   = (const float*)d_in[6];
  const float* temp = (const float*)d_in[7];
  const float* Wl   = (const float*)d_in[8];
  const float* bl   = (const float*)d_in[9];
  float* out = (float*)d_out;

  int Nn = in_sizes[0] / 512;     // 100000
  int E  = in_sizes[1] / 2;       // 3200000
  int Kk = in_sizes[7] - 1;       // 10

  char* p = (char*)d_ws;
  auto alloc = [&](size_t bytes) {
    char* r = p;
    p += (bytes + 255) & ~(size_t)255;
    return r;
  };
  int*   counts   = (int*)alloc((size_t)Nn * 4);
  int*   rowptr   = (int*)alloc((size_t)(Nn + 1) * 4);
  int*   incl     = (int*)alloc((size_t)Nn * 4);
  int*   partials = (int*)alloc(256 * 4);
  int*   chunkoff = (int*)alloc(256 * 4);
  int*   cursor   = (int*)alloc((size_t)Nn * 4);
  float* dinv     = (float*)alloc((size_t)Nn * 4);
  int*   srcoff   = (int*)alloc((size_t)E * 4);
  float* Hbuf     = (float*)alloc((size_t)Nn * 64 * 4);
  float* Mm       = (float*)alloc(2560 * 4);
  float* cv       = (float*)alloc(64 * 4);
  _Float16* W1T   = (_Float16*)alloc(64 * 512 * 2);
  int yboff = (Nn + 1) * 64;                       // byte offset of yb region
  size_t ybytes = (size_t)(Nn + 1) * 80;           // ya (64B rows) + yb (16B rows)
  char*  yA       = (char*)alloc(ybytes);
  char*  yB       = (char*)alloc(ybytes);
  float* hid      = (float*)alloc((size_t)Nn * 40 * 4);

  // bucketed CSR-build scratch
  int nb  = (Nn + 2047) >> 11;          // 49 buckets of 2048 nodes
  int nbx = (nb + 7) / 8;               // bucket slots per XCD class
  int cap = E / nb + E / (nb * 8) + 1024;  // per-bucket capacity (~13% headroom)
  unsigned long long* barr = (unsigned long long*)alloc((size_t)nb * cap * 8);
  int* bcnt = (int*)alloc(64 * 4);

  hipMemsetAsync(cursor, 0, (size_t)Nn * 4, stream);
  hipMemsetAsync(bcnt, 0, 64 * 4, stream);

  bucketA_kernel<<<(E + 2047) / 2048, 256, 0, stream>>>(edge, barr, bcnt, E, cap);
  countB_kernel<<<nb, 256, 0, stream>>>(barr, bcnt, counts, dinv, cap, Nn);
  int B = (Nn + 1023) / 1024;
  scanA_kernel<<<B, 256, 0, stream>>>(counts, incl, partials, Nn);
  scanB_kernel<<<1, 256, 0, stream>>>(partials, chunkoff, B);
  finalize_scan_kernel<<<(Nn + 255) / 256, 256, 0, stream>>>(incl, chunkoff, rowptr, Nn);
  int cpb = 32;
  fillB_kernel<<<8 * nbx * cpb, 256, 0, stream>>>(barr, bcnt, rowptr, cursor, srcoff,
                                                  cap, nb, nbx, cpb);

  w1t_kernel<<<128, 256, 0, stream>>>(W1, W1T);
  mlp1_mfma_kernel<<<(Nn + 63) / 64, 256, 0, stream>>>(X, W1T, b1, Hbuf, Nn);
  computeM_kernel<<<1, 256, 0, stream>>>(W2, Wl, b2, Mm, cv);
  zeropad_kernel<<<1, 64, 0, stream>>>(yA, yB, Nn, yboff);

  int nodeBlocks = (Nn + 3) / 4;
  z0_kernel<<<nodeBlocks, 256, 0, stream>>>(Hbuf, Mm, cv, dinv, temp, yA, hid, Nn, yboff);

  char* yin = yA;
  char* yout = yB;
  for (int k = 1; k <= Kk; ++k) {
    prop_kernel<<<nodeBlocks, 256, 0, stream>>>(yin, yout, hid, srcoff, rowptr, dinv,
                                                temp, k, Nn, yboff);
    char* tmpp = yin; yin = yout; yout = tmpp;
  }

  final_kernel<<<nodeBlocks, 256, 0, stream>>>(glob, Wl, bl, hid, counts, dinv, out, Nn);
}